// Round 4
// baseline (155.641 us; speedup 1.0000x reference)
//
#include <hip/hip_runtime.h>
#include <math.h>

#define Bsz 4096
#define Dk 128
#define ROWS_PER_BLOCK 64
#define COL_SPLIT 8
#define COLS_PER_BLOCK (Bsz / COL_SPLIT)        // 512
#define THREADS 256
#define WAVES 4
#define COLS_PER_WAVE (COLS_PER_BLOCK / WAVES)  // 128
#define CT_PER_WAVE (COLS_PER_WAVE / 16)        // 8
#define RT (ROWS_PER_BLOCK / 16)                // 4

typedef __attribute__((ext_vector_type(8))) short short8;
typedef __attribute__((ext_vector_type(4))) float f32x4;
typedef _Float16 half8 __attribute__((ext_vector_type(8)));
typedef _Float16 half4 __attribute__((ext_vector_type(4)));

__device__ __forceinline__ unsigned short f2bf(float f) {
  unsigned u = __float_as_uint(f);
  u = (u + 0x7fffu + ((u >> 16) & 1u)) >> 16;   // RNE
  return (unsigned short)u;
}

// X fp32 [4096][128] -> bf16 [4096][128]; also zero the atomic accumulators
// (must happen every launch: atomics accumulate and ws is not re-poisoned).
__global__ __launch_bounds__(256)
void convert_kernel(const float* __restrict__ X, short* __restrict__ Xb,
                    unsigned long long* __restrict__ acc) {
  int i = blockIdx.x * 256 + threadIdx.x;     // 65536 threads x 8 elems
  if (i < 4) acc[i] = 0ull;                    // [0]=sum_fx [1]=cnt [2]=done
  const float4* q = (const float4*)X + i * 2;
  float4 v0 = q[0], v1 = q[1];
  short8 r;
  r[0] = (short)f2bf(v0.x); r[1] = (short)f2bf(v0.y);
  r[2] = (short)f2bf(v0.z); r[3] = (short)f2bf(v0.w);
  r[4] = (short)f2bf(v1.x); r[5] = (short)f2bf(v1.y);
  r[6] = (short)f2bf(v1.z); r[7] = (short)f2bf(v1.w);
  ((short8*)Xb)[i] = r;
}

// Phase A: pure GEMM -> encoded fp16 sim store. enc: self->8, eq->sim+4, else sim.
// enc is exactly symmetric (MFMA dot order identical under operand swap), so each
// tile is stored TRANSPOSED: 4 acc regs = 4 consecutive rows -> one packed 8B store.
// No epilogue reductions at all (phaseB recomputes row min/max from the row itself).
__global__ __launch_bounds__(THREADS)
void phaseA(const short* __restrict__ Xb, const int* __restrict__ labels,
            _Float16* __restrict__ sim16) {
  const int tid = threadIdx.x;
  const int w  = tid >> 6;
  const int l  = tid & 63;
  const int lg = l >> 4;     // k-group / C row-group
  const int lr = l & 15;     // A row-in-tile / B,C col-in-tile
  const int by = blockIdx.x / COL_SPLIT;
  const int bx = blockIdx.x % COL_SPLIT;
  const int r0 = by * ROWS_PER_BLOCK;
  const int c0 = bx * COLS_PER_BLOCK + w * COLS_PER_WAVE;

  // A fragments: 64 rows x K=128, bf16, in registers (64 VGPR).
  short8 afrag[RT][4];
  for (int rt = 0; rt < RT; ++rt) {
    int row = r0 + rt * 16 + lr;
    for (int ks = 0; ks < 4; ++ks)
      afrag[rt][ks] = *(const short8*)(Xb + row * Dk + ks * 32 + lg * 8);
  }

  int labr[RT * 4];
  for (int rt = 0; rt < RT; ++rt)
    for (int rg = 0; rg < 4; ++rg)
      labr[rt * 4 + rg] = labels[r0 + rt * 16 + lg * 4 + rg];

  for (int ct = 0; ct < CT_PER_WAVE; ++ct) {
    const int ctc  = c0 + ct * 16;
    const int colv = ctc + lr;
    short8 bfrag[4];
    for (int ks = 0; ks < 4; ++ks)
      bfrag[ks] = *(const short8*)(Xb + colv * Dk + ks * 32 + lg * 8);
    const int labc = labels[colv];

    for (int rt = 0; rt < RT; ++rt) {
      f32x4 acc = {0.f, 0.f, 0.f, 0.f};
      for (int ks = 0; ks < 4; ++ks)
        acc = __builtin_amdgcn_mfma_f32_16x16x32_bf16(afrag[rt][ks], bfrag[ks], acc, 0, 0, 0);
      const bool diag = (ctc == r0 + rt * 16);   // wave-uniform
      half4 h;
      // C/D layout (verified): col = lane&15, row = (lane>>4)*4 + reg
      for (int rg = 0; rg < 4; ++rg) {
        float s    = acc[rg];
        bool  eq   = (labc == labr[rt * 4 + rg]);
        bool  self = diag && (lr == lg * 4 + rg);
        float enc  = eq ? s + 4.0f : s;
        if (self) enc = 8.0f;
        h[rg] = (_Float16)enc;
      }
      // transposed packed store: sim16[colv][r0+rt*16+lg*4 .. +3]
      *(half4*)(sim16 + (size_t)colv * Bsz + r0 + rt * 16 + lg * 4) = h;
    }
  }
}

// Phase B (fused with finalize): one row per wave. Row held in registers;
// pass 1 derives min_pos/max_neg, pass 2 the thresholded exp sums. Row losses
// are accumulated in fixed-point (2^32) integer atomics -> exact, deterministic.
// Last block computes the final mean.
__global__ __launch_bounds__(THREADS)
void phaseB(const _Float16* __restrict__ sim16,
            unsigned long long* __restrict__ acc, float* __restrict__ out) {
  const int w = threadIdx.x >> 6;
  const int l = threadIdx.x & 63;
  const int r = blockIdx.x * WAVES + w;

  const half8* base = (const half8*)(sim16 + (size_t)r * Bsz);
  half8 h[8];
#pragma unroll
  for (int ch = 0; ch < 8; ++ch) h[ch] = base[ch * 64 + l];

  // pass 1: min over eq (v>2) of v, max over !eq of v. self (v=8) joins the
  // eq-min harmlessly: if no real positive exists mnv stays 8 -> min_pos=4 -> invalid.
  float mnv = 8.0f, mxv = -INFINITY;
#pragma unroll
  for (int ch = 0; ch < 8; ++ch)
#pragma unroll
    for (int j = 0; j < 8; ++j) {
      float v  = (float)h[ch][j];
      bool  eq = v > 2.0f;
      mnv = (eq && v < mnv) ? v : mnv;
      mxv = (!eq && v > mxv) ? v : mxv;
    }
  for (int m = 1; m < 64; m <<= 1) {
    mnv = fminf(mnv, __shfl_xor(mnv, m, 64));
    mxv = fmaxf(mxv, __shfl_xor(mxv, m, 64));
  }
  const float thp = mxv + 4.1f;   // pos_keep: (v-4)-0.1 < max_neg  <=> v < thp
  const float thn = mnv - 4.1f;   // neg_keep: v+0.1 > (mnv-4)      <=> v > thn

  // pass 2: thresholded exp sums (exp2-form, single transcendental per elem)
  float ap = 0.f, an = 0.f;
#pragma unroll
  for (int ch = 0; ch < 8; ++ch)
#pragma unroll
    for (int j = 0; j < 8; ++j) {
      float v  = (float)h[ch][j];
      bool  eq = v > 2.0f;
      bool  kp = eq && (v < thp);            // self v=8 >= thp(<=5.1) -> excluded
      bool  kn = !eq && (v > thn);
      float argp = fmaf(v, -2.88539008f, 12.98425537f);   // -2*(v-4.5)*log2e
      float argn = fmaf(v, 57.70780163f, -28.85390082f);  // 40*(v-0.5)*log2e
      float e = exp2f(kp ? argp : argn);
      ap += kp ? e : 0.f;
      an += kn ? e : 0.f;
    }
  for (int m = 1; m < 64; m <<= 1) {
    ap += __shfl_xor(ap, m, 64);
    an += __shfl_xor(an, m, 64);
  }

  if (l == 0) {
    bool valid = thn < mxv;   // min_pos - 0.1 < max_neg  (== both any-kept conditions)
    float row = valid ? (log1pf(ap) * 0.5f + log1pf(an) * 0.025f) : 0.0f;
    unsigned long long fx = (unsigned long long)(long long)(row * 4294967296.0f);
    atomicAdd(&acc[0], fx);
    atomicAdd(&acc[1], (unsigned long long)(valid ? 1 : 0));
  }
  __syncthreads();                 // drains the waves' atomics (vmcnt) before signal
  if (threadIdx.x == 0) {
    __threadfence();
    unsigned long long old = atomicAdd(&acc[2], 1ull);
    if (old == (unsigned long long)(gridDim.x - 1)) {   // last block finalizes
      unsigned long long s = atomicAdd(&acc[0], 0ull);
      unsigned long long c = atomicAdd(&acc[1], 0ull);
      out[0] = (float)((double)(long long)s / 4294967296.0 / (double)(c ? c : 1ull));
    }
  }
}

extern "C" void kernel_launch(void* const* d_in, const int* in_sizes, int n_in,
                              void* d_out, int out_size, void* d_ws, size_t ws_size,
                              hipStream_t stream) {
  const float* X      = (const float*)d_in[0];
  const int*   labels = (const int*)d_in[1];

  char* ws = (char*)d_ws;
  _Float16*           sim16 = (_Float16*)(ws);                    // 32 MB
  short*              Xb    = (short*)(ws + 33554432);            // 1 MB
  unsigned long long* acc   = (unsigned long long*)(ws + 33554432 + 1048576);

  convert_kernel<<<256, 256, 0, stream>>>(X, Xb, acc);
  phaseA<<<(Bsz / ROWS_PER_BLOCK) * COL_SPLIT, THREADS, 0, stream>>>(Xb, labels, sim16);
  phaseB<<<Bsz / WAVES, THREADS, 0, stream>>>(sim16, acc, (float*)d_out);
}

// Round 5
// 57.519 us; speedup vs baseline: 2.7059x; 2.7059x over previous
//
#include <hip/hip_runtime.h>
#include <math.h>

#define Bsz 4096
#define Dk 128
#define RPB 32                  // rows per phaseA block
#define COL_SPLIT 8
#define CPB (Bsz / COL_SPLIT)   // 512 cols per block
#define THREADS 256
#define WAVES 4
#define CPW (CPB / WAVES)       // 128 cols per wave
#define CT (CPW / 16)           // 8 col-tiles per wave
#define RT (RPB / 16)           // 2 row-tiles
#define LDSW 520                // padded LDS row (breaks bank patterns, keeps 16B align: 520*2=1040=65*16)

typedef __attribute__((ext_vector_type(8))) short short8;
typedef __attribute__((ext_vector_type(4))) float f32x4;
typedef _Float16 half8 __attribute__((ext_vector_type(8)));

__device__ __forceinline__ unsigned short f2bf(float f) {
  unsigned u = __float_as_uint(f);
  u = (u + 0x7fffu + ((u >> 16) & 1u)) >> 16;   // RNE
  return (unsigned short)u;
}

// X fp32 [4096][128] -> bf16 [4096][128]
__global__ __launch_bounds__(256)
void convert_kernel(const float* __restrict__ X, short* __restrict__ Xb) {
  int i = blockIdx.x * 256 + threadIdx.x;     // 65536 threads x 8 elems
  const float4* q = (const float4*)X + i * 2;
  float4 v0 = q[0], v1 = q[1];
  short8 r;
  r[0] = (short)f2bf(v0.x); r[1] = (short)f2bf(v0.y);
  r[2] = (short)f2bf(v0.z); r[3] = (short)f2bf(v0.w);
  r[4] = (short)f2bf(v1.x); r[5] = (short)f2bf(v1.y);
  r[6] = (short)f2bf(v1.z); r[7] = (short)f2bf(v1.w);
  ((short8*)Xb)[i] = r;
}

// Phase A: GEMM -> encoded fp16 sim (self->8, eq->sim+4, else sim), staged in
// LDS and stored ROW-MAJOR as 1KB contiguous segments (no scatter, no write
// amplification). Also emits per-row min(pos)/max(neg) fp32 partials so phaseB
// is single-pass.
__global__ __launch_bounds__(THREADS, 4)
void phaseA(const short* __restrict__ Xb, const int* __restrict__ labels,
            _Float16* __restrict__ sim16,
            float* __restrict__ min_part, float* __restrict__ max_part) {
  const int tid = threadIdx.x;
  const int w  = tid >> 6;
  const int l  = tid & 63;
  const int lg = l >> 4;     // k-group / C row-group
  const int lr = l & 15;     // A row-in-tile / B,C col-in-tile
  const int by = blockIdx.x / COL_SPLIT;
  const int bx = blockIdx.x % COL_SPLIT;
  const int r0 = by * RPB;
  const int c0 = bx * CPB + w * CPW;

  __shared__ __align__(16) _Float16 tile[RPB][LDSW];   // 33,280 B
  __shared__ float red[2][WAVES][RPB];                 // 1 KB

  // A fragments: 32 rows x K=128 bf16 in registers (32 VGPR).
  short8 afrag[RT][4];
  for (int rt = 0; rt < RT; ++rt) {
    int row = r0 + rt * 16 + lr;
    for (int ks = 0; ks < 4; ++ks)
      afrag[rt][ks] = *(const short8*)(Xb + row * Dk + ks * 32 + lg * 8);
  }

  int labr[RT * 4];
  for (int rt = 0; rt < RT; ++rt)
    for (int rg = 0; rg < 4; ++rg)
      labr[rt * 4 + rg] = labels[r0 + rt * 16 + lg * 4 + rg];

  float mn[RT * 4], mx[RT * 4];
  for (int i = 0; i < RT * 4; ++i) { mn[i] = INFINITY; mx[i] = -INFINITY; }

  for (int ct = 0; ct < CT; ++ct) {
    const int ctc  = c0 + ct * 16;
    const int colv = ctc + lr;
    short8 bfrag[4];
    for (int ks = 0; ks < 4; ++ks)
      bfrag[ks] = *(const short8*)(Xb + colv * Dk + ks * 32 + lg * 8);
    const int labc = labels[colv];

    for (int rt = 0; rt < RT; ++rt) {
      f32x4 acc = {0.f, 0.f, 0.f, 0.f};
      for (int ks = 0; ks < 4; ++ks)
        acc = __builtin_amdgcn_mfma_f32_16x16x32_bf16(afrag[rt][ks], bfrag[ks], acc, 0, 0, 0);
      const bool diag = (ctc == r0 + rt * 16);   // wave-uniform
      const int  lcol = w * CPW + ct * 16 + lr;  // tile-local col
      // C/D layout (verified): col = lane&15, row = (lane>>4)*4 + reg
      for (int rg = 0; rg < 4; ++rg) {
        int   i    = rt * 4 + rg;
        float s    = acc[rg];
        bool  eq   = (labc == labr[i]);
        bool  self = diag && (lr == lg * 4 + rg);
        if (eq && !self) mn[i] = fminf(mn[i], s);
        if (!eq)         mx[i] = fmaxf(mx[i], s);
        float enc = eq ? s + 4.0f : s;
        if (self) enc = 8.0f;
        tile[rt * 16 + lg * 4 + rg][lcol] = (_Float16)enc;
      }
    }
  }

  // min/max reduce across the 16 col-lanes sharing each row
  for (int i = 0; i < RT * 4; ++i) {
    for (int m = 1; m < 16; m <<= 1) {
      float o0 = __shfl_xor(mn[i], m, 64);
      float o1 = __shfl_xor(mx[i], m, 64);
      mn[i] = fminf(mn[i], o0);
      mx[i] = fmaxf(mx[i], o1);
    }
  }
  if (lr == 0) {
    for (int i = 0; i < RT * 4; ++i) {
      int rt = i >> 2, rg = i & 3;
      red[0][w][rt * 16 + lg * 4 + rg] = mn[i];
      red[1][w][rt * 16 + lg * 4 + rg] = mx[i];
    }
  }
  __syncthreads();

  if (tid < RPB) {
    float v0 = INFINITY, v1 = -INFINITY;
    for (int ww = 0; ww < WAVES; ++ww) {
      v0 = fminf(v0, red[0][ww][tid]);
      v1 = fmaxf(v1, red[1][ww][tid]);
    }
    min_part[bx * Bsz + r0 + tid] = v0;
    max_part[bx * Bsz + r0 + tid] = v1;
  }

  // coalesced row-major store: each wave 8 rows, 1KB contiguous per row
  for (int k = 0; k < RPB / WAVES; ++k) {
    int rr = w * (RPB / WAVES) + k;
    float4 v = *(const float4*)&tile[rr][l * 8];
    *(float4*)(sim16 + (size_t)(r0 + rr) * Bsz + bx * CPB + l * 8) = v;
  }
}

// Phase B: one row per BLOCK (4096 blocks), single pass, thresholds from partials.
__global__ __launch_bounds__(THREADS)
void phaseB(const _Float16* __restrict__ sim16,
            const float* __restrict__ min_part, const float* __restrict__ max_part,
            float* __restrict__ row_loss, float* __restrict__ row_valid) {
  const int r = blockIdx.x;
  const int t = threadIdx.x;
  const int l = t & 63;

  float mnr = INFINITY, mxr = -INFINITY;
  for (int b = 0; b < COL_SPLIT; ++b) {
    mnr = fminf(mnr, min_part[b * Bsz + r]);
    mxr = fmaxf(mxr, max_part[b * Bsz + r]);
  }
  const float thp = mxr + 4.1f;   // pos_keep: (v-4)-0.1 < max_neg  <=> v < thp
  const float thn = mnr - 0.1f;   // neg_keep: v+0.1 > min_pos      <=> v > thn

  const half8* base = (const half8*)(sim16 + (size_t)r * Bsz);
  half8 h0 = base[t], h1 = base[t + 256];

  float ap = 0.f, an = 0.f;
#pragma unroll
  for (int c = 0; c < 2; ++c) {
    half8 h = c ? h1 : h0;
#pragma unroll
    for (int j = 0; j < 8; ++j) {
      float v  = (float)h[j];
      bool  eq = v > 2.0f;
      bool  kp = eq && (v < thp);            // self v=8 >= thp(<=5.1) -> excluded
      bool  kn = !eq && (v > thn);
      float argp = fmaf(v, -2.88539008f, 12.98425537f);   // -2*(v-4.5)*log2e
      float argn = fmaf(v, 57.70780163f, -28.85390082f);  // 40*(v-0.5)*log2e
      float e = exp2f(kp ? argp : argn);
      ap += kp ? e : 0.f;
      an += kn ? e : 0.f;
    }
  }
  for (int m = 1; m < 64; m <<= 1) {
    ap += __shfl_xor(ap, m, 64);
    an += __shfl_xor(an, m, 64);
  }

  __shared__ float sred[2][WAVES];
  if (l == 0) { sred[0][t >> 6] = ap; sred[1][t >> 6] = an; }
  __syncthreads();
  if (t == 0) {
    float tap = 0.f, tan = 0.f;
    for (int ww = 0; ww < WAVES; ++ww) { tap += sred[0][ww]; tan += sred[1][ww]; }
    bool valid = (mnr - 0.1f < mxr);   // == any-pos-kept && any-neg-kept
    row_loss[r]  = valid ? (log1pf(tap) * 0.5f + log1pf(tan) * 0.025f) : 0.0f;
    row_valid[r] = valid ? 1.0f : 0.0f;
  }
}

__global__ __launch_bounds__(1024)
void finalize(const float* __restrict__ row_loss, const float* __restrict__ row_valid,
              float* __restrict__ out) {
  int tid = threadIdx.x;
  float s = 0.f, c = 0.f;
  for (int r = tid; r < Bsz; r += 1024) {
    s += row_loss[r];
    c += row_valid[r];
  }
  for (int m = 1; m < 64; m <<= 1) {
    s += __shfl_xor(s, m, 64);
    c += __shfl_xor(c, m, 64);
  }
  __shared__ float rs[16], rc[16];
  int w = tid >> 6, lz = tid & 63;
  if (lz == 0) { rs[w] = s; rc[w] = c; }
  __syncthreads();
  if (tid == 0) {
    float ts = 0.f, tc = 0.f;
    for (int i = 0; i < 16; ++i) { ts += rs[i]; tc += rc[i]; }
    out[0] = ts / fmaxf(tc, 1.0f);
  }
}

extern "C" void kernel_launch(void* const* d_in, const int* in_sizes, int n_in,
                              void* d_out, int out_size, void* d_ws, size_t ws_size,
                              hipStream_t stream) {
  const float* X      = (const float*)d_in[0];
  const int*   labels = (const int*)d_in[1];

  char* ws = (char*)d_ws;
  _Float16* sim16    = (_Float16*)(ws);                               // 32 MB
  short*    Xb       = (short*)(ws + 33554432);                       // 1 MB
  float*    min_part = (float*)(ws + 33554432 + 1048576);             // 128 KB
  float*    max_part = (float*)(ws + 33554432 + 1048576 + 131072);    // 128 KB
  float*    row_loss = (float*)(ws + 33554432 + 1048576 + 262144);    // 16 KB
  float*    row_valid= (float*)(ws + 33554432 + 1048576 + 278528);    // 16 KB

  convert_kernel<<<256, 256, 0, stream>>>(X, Xb);
  phaseA<<<(Bsz / RPB) * COL_SPLIT, THREADS, 0, stream>>>(Xb, labels, sim16, min_part, max_part);
  phaseB<<<Bsz, THREADS, 0, stream>>>(sim16, min_part, max_part, row_loss, row_valid);
  finalize<<<1, 1024, 0, stream>>>(row_loss, row_valid, (float*)d_out);
}